// Round 8
// baseline (290.641 us; speedup 1.0000x reference)
//
#include <hip/hip_runtime.h>

#define DD 128
#define NB 8
#define KTOT 1152   // 1024 (agg: k = kk*8 + b) + 128 (self-loop h)

typedef unsigned int uint_t;
typedef __attribute__((ext_vector_type(8))) _Float16 half8v;
typedef __attribute__((ext_vector_type(2))) _Float16 half2v;
typedef __attribute__((ext_vector_type(4))) float f32x4;

static __device__ __forceinline__ void gld_lds16(const _Float16* g, _Float16* l)
{
  __builtin_amdgcn_global_load_lds(
      (const __attribute__((address_space(1))) void*)g,
      (__attribute__((address_space(3))) void*)l, 16, 0, 0);
}

static __device__ __forceinline__ half2v bc_h2(uint_t u)
{
  union { uint_t u; half2v h; } c; c.u = u; return c.h;
}

static __device__ __forceinline__ float fdot2(uint_t a, uint_t b, float acc)
{
#if __has_builtin(__builtin_amdgcn_fdot2)
  return __builtin_amdgcn_fdot2(bc_h2(a), bc_h2(b), acc, false);
#else
  half2v x = bc_h2(a), y = bc_h2(b);
  return acc + (float)x[0] * (float)y[0] + (float)x[1] * (float)y[1];
#endif
}

// ---------------------------------------------------------------------------
// WcA[layer][ks][feat][j] = W[feat][k=ks*32+j]   (A-fragment-coalesced layout)
//   k<1024 -> bases[b=k&7][kk=k>>3][feat]; else loop_w[k-1024][feat]
// ---------------------------------------------------------------------------
__global__ __launch_bounds__(256) void k_prep_w(
    const float* __restrict__ bases1, const float* __restrict__ loopw1,
    const float* __restrict__ bases2, const float* __restrict__ loopw2,
    _Float16* __restrict__ WcA)
{
  int i = blockIdx.x * 256 + threadIdx.x;          // 2*36*128*32
  if (i >= 2 * 36 * DD * 32) return;
  int layer = i / (36 * DD * 32);
  int rem   = i % (36 * DD * 32);
  int ks    = rem / (DD * 32);
  int rem2  = rem % (DD * 32);
  int feat  = rem2 / 32;
  int j     = rem2 % 32;
  int k     = ks * 32 + j;
  const float* basesL = layer ? bases2 : bases1;
  const float* loopwL = layer ? loopw2 : loopw1;
  float v;
  if (k < 1024) {
    int kk = k >> 3, b = k & 7;
    v = basesL[((size_t)b * DD + kk) * DD + feat];
  } else {
    v = loopwL[(size_t)(k - 1024) * DD + feat];
  }
  WcA[i] = (_Float16)v;
}

// cast h (fp32, ids indirection) -> fp16 [N][128]
__global__ __launch_bounds__(256) void k_cast(
    const float* __restrict__ h, const int* __restrict__ ids,
    _Float16* __restrict__ hf, int N)
{
  int i = blockIdx.x * 256 + threadIdx.x;
  if (i >= N * (DD / 8)) return;
  int n  = i / (DD / 8);
  int k8 = (i % (DD / 8)) * 8;
  int row = ids ? ids[n] : n;
  const float* hp = h + (size_t)row * DD + k8;
  float4 v0 = *(const float4*)hp;
  float4 v1 = *(const float4*)(hp + 4);
  union { _Float16 e[8]; uint4 q; } p;
  p.e[0]=(_Float16)v0.x; p.e[1]=(_Float16)v0.y; p.e[2]=(_Float16)v0.z; p.e[3]=(_Float16)v0.w;
  p.e[4]=(_Float16)v1.x; p.e[5]=(_Float16)v1.y; p.e[6]=(_Float16)v1.z; p.e[7]=(_Float16)v1.w;
  *(uint4*)&hf[(size_t)n * DD + k8] = p.q;
}

// ------------------------------- CSR by dst --------------------------------
// Segments are padded to EVEN length (pads have zero coefficients), so the
// aggregation loop can always process edge PAIRS with v_dot2_f32_f16.
__global__ __launch_bounds__(256) void k_zero(int* __restrict__ p, int n)
{
  int i = blockIdx.x * 256 + threadIdx.x;
  if (i < n) p[i] = 0;
}

__global__ __launch_bounds__(256) void k_hist(
    const int* __restrict__ dst, int* __restrict__ cnt, int E)
{
  int e = blockIdx.x * 256 + threadIdx.x;
  if (e < E) atomicAdd(&cnt[dst[e]], 1);
}

__global__ __launch_bounds__(256) void k_bsum(
    const int* __restrict__ cnt, int* __restrict__ bsum, int N)
{
  __shared__ int s[256];
  int i = blockIdx.x * 256 + threadIdx.x;
  s[threadIdx.x] = (i < N) ? ((cnt[i] + 1) & ~1) : 0;   // padded counts
  __syncthreads();
  for (int off = 128; off > 0; off >>= 1) {
    if (threadIdx.x < off) s[threadIdx.x] += s[threadIdx.x + off];
    __syncthreads();
  }
  if (threadIdx.x == 0) bsum[blockIdx.x] = s[0];
}

__global__ __launch_bounds__(256) void k_scanb(
    const int* __restrict__ bsum, int* __restrict__ boff, int nb)
{
  __shared__ int s[256];
  int t = threadIdx.x;
  int own = (t < nb) ? bsum[t] : 0;
  s[t] = own;
  __syncthreads();
  for (int off = 1; off < 256; off <<= 1) {
    int v = (t >= off) ? s[t - off] : 0;
    __syncthreads();
    s[t] += v;
    __syncthreads();
  }
  if (t < nb) boff[t] = s[t] - own;     // exclusive
}

__global__ __launch_bounds__(256) void k_scan3(
    const int* __restrict__ cnt, const int* __restrict__ boff,
    int* __restrict__ row_start, int N)
{
  __shared__ int s[256];
  int t = threadIdx.x;
  int i = blockIdx.x * 256 + t;
  int v = (i < N) ? ((cnt[i] + 1) & ~1) : 0;            // padded counts
  s[t] = v;
  __syncthreads();
  for (int off = 1; off < 256; off <<= 1) {
    int u = (t >= off) ? s[t - off] : 0;
    __syncthreads();
    s[t] += u;
    __syncthreads();
  }
  if (i < N) row_start[i] = boff[blockIdx.x] + s[t] - v;
}

// ---------------------------------------------------------------------------
// Place + payload in one pass: edge e -> slot; write psrc[slot] and the fp16
// coefficients in PAIR-INTERLEAVED layout: c[pair][b][parity].
// Pad slots keep their pre-zeroed psrc=0 / c=0 (zero contribution).
// ---------------------------------------------------------------------------
__global__ __launch_bounds__(256) void k_place_payload(
    const int* __restrict__ dst, const int* __restrict__ src,
    const int* __restrict__ etype, const float* __restrict__ norm,
    const float* __restrict__ wcomp1, const float* __restrict__ wcomp2,
    const int* __restrict__ rowst, int* __restrict__ cursor,
    int* __restrict__ psrc, _Float16* __restrict__ c1, _Float16* __restrict__ c2,
    int E)
{
  int e = blockIdx.x * 256 + threadIdx.x;
  if (e >= E) return;
  int v = dst[e];
  int slot = rowst[v] + atomicAdd(&cursor[v], 1);
  psrc[slot] = src[e];
  int t = etype[e];
  float nm = norm[e];
  const float* w1 = wcomp1 + t * NB;
  const float* w2 = wcomp2 + t * NB;
  size_t base = (size_t)(slot >> 1) * 16 + (slot & 1);
  #pragma unroll
  for (int b = 0; b < NB; b++) c1[base + b * 2] = (_Float16)(w1[b] * nm);
  #pragma unroll
  for (int b = 0; b < NB; b++) c2[base + b * 2] = (_Float16)(w2[b] * nm);
}

// ---------------------------------------------------------------------------
// Aggregation: one wave per dst node; edge-pair inner loop with fdot2.
// agg[v][kk*8+b] = sum_edges c[slot][b] * hf[psrc[slot]][kk]   (fp16)
// Per 4 edges: 4 gathers + 4 v_perm + 32 v_dot2_f32_f16.
// ---------------------------------------------------------------------------
__global__ __launch_bounds__(256) void k_agg(
    const int* __restrict__ rowst, const int* __restrict__ cnt,
    const int* __restrict__ psrc, const _Float16* __restrict__ cpair,
    const _Float16* __restrict__ hf,
    _Float16* __restrict__ agg, int N)
{
  int v = blockIdx.x * 4 + (threadIdx.x >> 6);
  if (v >= N) return;
  int lane = threadIdx.x & 63;
  const uint_t* hf32 = (const uint_t*)hf;
  const int beg = rowst[v];                    // even by construction
  const int npairs = (cnt[v] + 1) >> 1;
  const uint_t* cp = (const uint_t*)cpair + (size_t)(beg >> 1) * 8;
  const int* ps = psrc + beg;

  float ax[NB] = {}, ay[NB] = {};
  int i = 0;
  for (; i + 2 <= npairs; i += 2) {
    int s0 = ps[2*i + 0], s1 = ps[2*i + 1];
    int s2 = ps[2*i + 2], s3 = ps[2*i + 3];
    uint_t u0 = hf32[(size_t)s0 * 64 + lane];
    uint_t u1 = hf32[(size_t)s1 * 64 + lane];
    uint_t u2 = hf32[(size_t)s2 * 64 + lane];
    uint_t u3 = hf32[(size_t)s3 * 64 + lane];
    uint_t lo01 = __builtin_amdgcn_perm(u0, u1, 0x01000504);
    uint_t hi01 = __builtin_amdgcn_perm(u0, u1, 0x03020706);
    uint_t lo23 = __builtin_amdgcn_perm(u2, u3, 0x01000504);
    uint_t hi23 = __builtin_amdgcn_perm(u2, u3, 0x03020706);
    #pragma unroll
    for (int b = 0; b < NB; b++) {
      uint_t ca = cp[(size_t)i * 8 + b];
      uint_t cb = cp[(size_t)(i + 1) * 8 + b];
      ax[b] = fdot2(ca, lo01, ax[b]);
      ay[b] = fdot2(ca, hi01, ay[b]);
      ax[b] = fdot2(cb, lo23, ax[b]);
      ay[b] = fdot2(cb, hi23, ay[b]);
    }
  }
  if (i < npairs) {
    int s0 = ps[2*i + 0], s1 = ps[2*i + 1];
    uint_t u0 = hf32[(size_t)s0 * 64 + lane];
    uint_t u1 = hf32[(size_t)s1 * 64 + lane];
    uint_t lo01 = __builtin_amdgcn_perm(u0, u1, 0x01000504);
    uint_t hi01 = __builtin_amdgcn_perm(u0, u1, 0x03020706);
    #pragma unroll
    for (int b = 0; b < NB; b++) {
      uint_t ca = cp[(size_t)i * 8 + b];
      ax[b] = fdot2(ca, lo01, ax[b]);
      ay[b] = fdot2(ca, hi01, ay[b]);
    }
  }

  union { _Float16 e[8]; uint4 q; } p0, p1;
  #pragma unroll
  for (int b = 0; b < NB; b++) { p0.e[b] = (_Float16)ax[b]; p1.e[b] = (_Float16)ay[b]; }
  uint4* dstp = (uint4*)&agg[(size_t)v * 1024 + lane * 16];
  dstp[0] = p0.q;
  dstp[1] = p1.q;
}

// ---------------------------------------------------------------------------
// MFMA GEMM, K=1152, BK=64, LDS-shared B with global_load_lds double-buffer.
// (unchanged from round 7)
// ---------------------------------------------------------------------------
template <int LAYER>
__global__ __launch_bounds__(256) void k_mm(
    const _Float16* __restrict__ agg,   // [N][1024]
    const _Float16* __restrict__ hf,    // [N][128]
    const _Float16* __restrict__ WcA,   // [36][128][32]
    const float* __restrict__ bias,
    float* __restrict__ outf, _Float16* __restrict__ outh, int N)
{
  __shared__ _Float16 sB[2][4096];      // 2 x 8KB

  const int n0   = blockIdx.x * 64;
  const int wv   = threadIdx.x >> 6;
  const int lane = threadIdx.x & 63;
  const int l15  = lane & 15, l4 = lane >> 4;

  int nodeL = n0 + lane; if (nodeL >= N) nodeL = N - 1;   // stage-source clamp

  f32x4 acc[2][4];
  #pragma unroll
  for (int a = 0; a < 2; a++)
    #pragma unroll
    for (int b = 0; b < 4; b++) acc[a][b] = (f32x4)0.f;

  const int fbase = wv * 32 + l15;      // + mf*16
  const int koff  = l4 * 8;

  auto STAGE = [&](int buf, int t) {
    const _Float16 *g0, *g1;
    if (t < 16) {
      g0 = &agg[(size_t)nodeL * 1024 + (2 * t)     * 32 + wv * 8];
      g1 = &agg[(size_t)nodeL * 1024 + (2 * t + 1) * 32 + wv * 8];
    } else {
      g0 = &hf[(size_t)nodeL * DD + (2 * t - 32) * 32 + wv * 8];
      g1 = &hf[(size_t)nodeL * DD + (2 * t - 31) * 32 + wv * 8];
    }
    gld_lds16(g0, &sB[buf][ wv      * 512]);
    gld_lds16(g1, &sB[buf][(wv + 4) * 512]);
  };

  auto COMPUTE = [&](int buf, int t) {
    #pragma unroll
    for (int sub = 0; sub < 2; sub++) {
      const int ks = 2 * t + sub;
      half8v af[2], bfr[4];
      #pragma unroll
      for (int mf = 0; mf < 2; mf++)
        af[mf] = *(const half8v*)&WcA[((size_t)ks * DD + fbase + mf * 16) * 32 + koff];
      #pragma unroll
      for (int nf = 0; nf < 4; nf++)
        bfr[nf] = *(const half8v*)&sB[buf][(l4 + sub * 4) * 512 + (nf * 16 + l15) * 8];
      #pragma unroll
      for (int mf = 0; mf < 2; mf++)
        #pragma unroll
        for (int nf = 0; nf < 4; nf++)
          acc[mf][nf] = __builtin_amdgcn_mfma_f32_16x16x32_f16(af[mf], bfr[nf], acc[mf][nf], 0, 0, 0);
    }
  };

  STAGE(0, 0);
  __syncthreads();
  int cur = 0;
  for (int t = 0; t < 17; t++) {
    STAGE(cur ^ 1, t + 1);
    COMPUTE(cur, t);
    __syncthreads();
    cur ^= 1;
  }
  COMPUTE(cur, 17);

  #pragma unroll
  for (int mf = 0; mf < 2; mf++)
    #pragma unroll
    for (int nf = 0; nf < 4; nf++) {
      int n = n0 + nf * 16 + l15;
      if (n >= N) continue;
      int feat = wv * 32 + mf * 16 + l4 * 4;
      if (LAYER == 1) {
        union { _Float16 e[4]; uint2 q; } p;
        #pragma unroll
        for (int r = 0; r < 4; r++)
          p.e[r] = (_Float16)fmaxf(acc[mf][nf][r] + bias[feat + r], 0.f);
        *(uint2*)&outh[(size_t)n * DD + feat] = p.q;
      } else {
        float4 o;
        o.x = acc[mf][nf][0] + bias[feat + 0];
        o.y = acc[mf][nf][1] + bias[feat + 1];
        o.z = acc[mf][nf][2] + bias[feat + 2];
        o.w = acc[mf][nf][3] + bias[feat + 3];
        *(float4*)&outf[(size_t)n * DD + feat] = o;
      }
    }
}

extern "C" void kernel_launch(void* const* d_in, const int* in_sizes, int n_in,
                              void* d_out, int out_size, void* d_ws, size_t ws_size,
                              hipStream_t stream)
{
  const int*   h_ids     = (const int*)d_in[0];
  const int*   src       = (const int*)d_in[1];
  const int*   dst       = (const int*)d_in[2];
  const int*   etype     = (const int*)d_in[3];
  const float* norm      = (const float*)d_in[4];
  const float* embedding = (const float*)d_in[5];
  const float* w_comp1   = (const float*)d_in[6];
  const float* bases1    = (const float*)d_in[7];
  const float* loop_w1   = (const float*)d_in[8];
  const float* bias1     = (const float*)d_in[9];
  const float* w_comp2   = (const float*)d_in[10];
  const float* bases2    = (const float*)d_in[11];
  const float* loop_w2   = (const float*)d_in[12];
  const float* bias2     = (const float*)d_in[13];

  const int N = in_sizes[0];
  const int E = in_sizes[1];
  const int S = E + N;                  // max padded slots
  const int NBLK = (N + 255) / 256;     // <= 256 (N <= 65536)

  // ---- workspace carve-up (256B aligned) ----
  char* base = (char*)d_ws;
  size_t off = 0;
  auto alloc = [&](size_t bytes) -> char* {
    char* p = base + off;
    off += (bytes + 255) & ~(size_t)255;
    return p;
  };
  _Float16* agg  = (_Float16*)alloc((size_t)N * 1024 * 2);   // 102.4 MB
  _Float16* hfp  = (_Float16*)alloc((size_t)N * DD * 2);     // 12.8 MB
  _Float16* h1h  = (_Float16*)alloc((size_t)N * DD * 2);     // 12.8 MB
  _Float16* WcA  = (_Float16*)alloc((size_t)2 * 36 * DD * 32 * 2);
  int*      cnt    = (int*)   alloc((size_t)2 * N * 4);      // cnt + cursor
  int*      cursor = cnt + N;
  int*      rowst  = (int*)   alloc((size_t)N * 4);
  int*      bsum   = (int*)   alloc(256 * 4);
  int*      boff   = (int*)   alloc(256 * 4);
  int*      psrc   = (int*)   alloc((size_t)S * 4);
  _Float16* c1     = (_Float16*)alloc((size_t)S * 8 * 2);    // 10.4 MB
  _Float16* c2     = (_Float16*)alloc((size_t)S * 8 * 2);    // 10.4 MB
  float*    out    = (float*)d_out;

  // ---- build padded CSR by dst (reused by both layers) ----
  k_zero <<<(2 * N + 255) / 256, 256, 0, stream>>>(cnt, 2 * N);
  k_zero <<<(S + 255) / 256, 256, 0, stream>>>(psrc, S);
  k_zero <<<(S * 4 + 255) / 256, 256, 0, stream>>>((int*)c1, S * 4);
  k_zero <<<(S * 4 + 255) / 256, 256, 0, stream>>>((int*)c2, S * 4);
  k_hist <<<(E + 255) / 256, 256, 0, stream>>>(dst, cnt, E);
  k_bsum <<<NBLK, 256, 0, stream>>>(cnt, bsum, N);
  k_scanb<<<1, 256, 0, stream>>>(bsum, boff, NBLK);
  k_scan3<<<NBLK, 256, 0, stream>>>(cnt, boff, rowst, N);
  k_place_payload<<<(E + 255) / 256, 256, 0, stream>>>(
      dst, src, etype, norm, w_comp1, w_comp2, rowst, cursor, psrc, c1, c2, E);

  // ---- weights -> fp16 A-coalesced layout ----
  k_prep_w<<<(2 * 36 * DD * 32 + 255) / 256, 256, 0, stream>>>(bases1, loop_w1, bases2, loop_w2, WcA);

  dim3 gmm((N + 63) / 64);
  int gagg = (N + 3) / 4;

  // ---- layer 1 ----
  k_cast<<<(N * (DD / 8) + 255) / 256, 256, 0, stream>>>(embedding, h_ids, hfp, N);
  k_agg<<<gagg, 256, 0, stream>>>(rowst, cnt, psrc, c1, hfp, agg, N);
  k_mm<1><<<gmm, 256, 0, stream>>>(agg, hfp, WcA, bias1, nullptr, h1h, N);

  // ---- layer 2 ----
  k_agg<<<gagg, 256, 0, stream>>>(rowst, cnt, psrc, c2, h1h, agg, N);
  k_mm<2><<<gmm, 256, 0, stream>>>(agg, h1h, WcA + (size_t)36 * DD * 32, bias2, out, nullptr, N);
}

// Round 9
// 276.249 us; speedup vs baseline: 1.0521x; 1.0521x over previous
//
#include <hip/hip_runtime.h>

#define DD 128
#define NB 8
#define KTOT 1152   // 1024 (agg: k = kk*8 + b) + 128 (self-loop h)

typedef unsigned int uint_t;
typedef __attribute__((ext_vector_type(8))) _Float16 half8v;
typedef __attribute__((ext_vector_type(2))) _Float16 half2v;
typedef __attribute__((ext_vector_type(4))) float f32x4;

static __device__ __forceinline__ void gld_lds16(const _Float16* g, _Float16* l)
{
  __builtin_amdgcn_global_load_lds(
      (const __attribute__((address_space(1))) void*)g,
      (__attribute__((address_space(3))) void*)l, 16, 0, 0);
}

static __device__ __forceinline__ half2v bc_h2(uint_t u)
{
  union { uint_t u; half2v h; } c; c.u = u; return c.h;
}

static __device__ __forceinline__ float fdot2(uint_t a, uint_t b, float acc)
{
#if __has_builtin(__builtin_amdgcn_fdot2)
  return __builtin_amdgcn_fdot2(bc_h2(a), bc_h2(b), acc, false);
#else
  half2v x = bc_h2(a), y = bc_h2(b);
  return acc + (float)x[0] * (float)y[0] + (float)x[1] * (float)y[1];
#endif
}

// ---------------------------------------------------------------------------
// WcA[layer][ks][feat][j] = W[feat][k=ks*32+j]   (A-fragment-coalesced layout)
//   k<1024 -> bases[b=k&7][kk=k>>3][feat]; else loop_w[k-1024][feat]
// ---------------------------------------------------------------------------
__global__ __launch_bounds__(256) void k_prep_w(
    const float* __restrict__ bases1, const float* __restrict__ loopw1,
    const float* __restrict__ bases2, const float* __restrict__ loopw2,
    _Float16* __restrict__ WcA)
{
  int i = blockIdx.x * 256 + threadIdx.x;          // 2*36*128*32
  if (i >= 2 * 36 * DD * 32) return;
  int layer = i / (36 * DD * 32);
  int rem   = i % (36 * DD * 32);
  int ks    = rem / (DD * 32);
  int rem2  = rem % (DD * 32);
  int feat  = rem2 / 32;
  int j     = rem2 % 32;
  int k     = ks * 32 + j;
  const float* basesL = layer ? bases2 : bases1;
  const float* loopwL = layer ? loopw2 : loopw1;
  float v;
  if (k < 1024) {
    int kk = k >> 3, b = k & 7;
    v = basesL[((size_t)b * DD + kk) * DD + feat];
  } else {
    v = loopwL[(size_t)(k - 1024) * DD + feat];
  }
  WcA[i] = (_Float16)v;
}

// cast h (fp32, ids indirection) -> fp16 [N][128]
__global__ __launch_bounds__(256) void k_cast(
    const float* __restrict__ h, const int* __restrict__ ids,
    _Float16* __restrict__ hf, int N)
{
  int i = blockIdx.x * 256 + threadIdx.x;
  if (i >= N * (DD / 8)) return;
  int n  = i / (DD / 8);
  int k8 = (i % (DD / 8)) * 8;
  int row = ids ? ids[n] : n;
  const float* hp = h + (size_t)row * DD + k8;
  float4 v0 = *(const float4*)hp;
  float4 v1 = *(const float4*)(hp + 4);
  union { _Float16 e[8]; uint4 q; } p;
  p.e[0]=(_Float16)v0.x; p.e[1]=(_Float16)v0.y; p.e[2]=(_Float16)v0.z; p.e[3]=(_Float16)v0.w;
  p.e[4]=(_Float16)v1.x; p.e[5]=(_Float16)v1.y; p.e[6]=(_Float16)v1.z; p.e[7]=(_Float16)v1.w;
  *(uint4*)&hf[(size_t)n * DD + k8] = p.q;
}

// ------------------------------- CSR by dst --------------------------------
// Segments padded to EVEN length; pad slots carry zero coefficients.
__global__ __launch_bounds__(256) void k_zero(int* __restrict__ p, int n)
{
  int i = blockIdx.x * 256 + threadIdx.x;
  if (i < n) p[i] = 0;
}

__global__ __launch_bounds__(256) void k_fill(int* __restrict__ p, int val, int n)
{
  int i = blockIdx.x * 256 + threadIdx.x;
  if (i < n) p[i] = val;
}

__global__ __launch_bounds__(256) void k_hist(
    const int* __restrict__ dst, int* __restrict__ cnt, int E)
{
  int e = blockIdx.x * 256 + threadIdx.x;
  if (e < E) atomicAdd(&cnt[dst[e]], 1);
}

__global__ __launch_bounds__(256) void k_bsum(
    const int* __restrict__ cnt, int* __restrict__ bsum, int N)
{
  __shared__ int s[256];
  int i = blockIdx.x * 256 + threadIdx.x;
  s[threadIdx.x] = (i < N) ? ((cnt[i] + 1) & ~1) : 0;   // padded counts
  __syncthreads();
  for (int off = 128; off > 0; off >>= 1) {
    if (threadIdx.x < off) s[threadIdx.x] += s[threadIdx.x + off];
    __syncthreads();
  }
  if (threadIdx.x == 0) bsum[blockIdx.x] = s[0];
}

__global__ __launch_bounds__(256) void k_scanb(
    const int* __restrict__ bsum, int* __restrict__ boff, int nb)
{
  __shared__ int s[256];
  int t = threadIdx.x;
  int own = (t < nb) ? bsum[t] : 0;
  s[t] = own;
  __syncthreads();
  for (int off = 1; off < 256; off <<= 1) {
    int v = (t >= off) ? s[t - off] : 0;
    __syncthreads();
    s[t] += v;
    __syncthreads();
  }
  if (t < nb) boff[t] = s[t] - own;     // exclusive
}

__global__ __launch_bounds__(256) void k_scan3(
    const int* __restrict__ cnt, const int* __restrict__ boff,
    int* __restrict__ row_start, int N)
{
  __shared__ int s[256];
  int t = threadIdx.x;
  int i = blockIdx.x * 256 + t;
  int v = (i < N) ? ((cnt[i] + 1) & ~1) : 0;            // padded counts
  s[t] = v;
  __syncthreads();
  for (int off = 1; off < 256; off <<= 1) {
    int u = (t >= off) ? s[t - off] : 0;
    __syncthreads();
    s[t] += u;
    __syncthreads();
  }
  if (i < N) row_start[i] = boff[blockIdx.x] + s[t] - v;
}

__global__ __launch_bounds__(256) void k_place(
    const int* __restrict__ dst, const int* __restrict__ row_start,
    int* __restrict__ cursor, int* __restrict__ perm, int E)
{
  int e = blockIdx.x * 256 + threadIdx.x;
  if (e < E) {
    int v = dst[e];
    int slot = row_start[v] + atomicAdd(&cursor[v], 1);
    perm[slot] = e;
  }
}

// ---------------------------------------------------------------------------
// Payload, one thread per slot PAIR: read perm linearly, gather per-edge
// scalars, write psrc (8B) + pair-interleaved fp16 coefficients
// (c[pair][b][parity], one 32B contiguous block per layer).  All stores
// coalesced with neighbor threads.  perm == -1 marks pad slots (zero coeffs).
// ---------------------------------------------------------------------------
__global__ __launch_bounds__(256) void k_payload_pair(
    const int* __restrict__ perm, const int* __restrict__ src,
    const int* __restrict__ etype, const float* __restrict__ norm,
    const float* __restrict__ wcomp1, const float* __restrict__ wcomp2,
    int* __restrict__ psrc, _Float16* __restrict__ c1, _Float16* __restrict__ c2,
    int npair)
{
  int i = blockIdx.x * 256 + threadIdx.x;
  if (i >= npair) return;
  int e0 = perm[2 * i], e1 = perm[2 * i + 1];

  int s0 = 0, s1 = 0;
  float n0 = 0.f, n1 = 0.f;
  const float *w10 = wcomp1, *w20 = wcomp2, *w11 = wcomp1, *w21 = wcomp2;
  if (e0 >= 0) { s0 = src[e0]; n0 = norm[e0]; int t = etype[e0]; w10 = wcomp1 + t * NB; w20 = wcomp2 + t * NB; }
  if (e1 >= 0) { s1 = src[e1]; n1 = norm[e1]; int t = etype[e1]; w11 = wcomp1 + t * NB; w21 = wcomp2 + t * NB; }

  *(int2*)&psrc[2 * i] = make_int2(s0, s1);

  union { _Float16 h[16]; uint4 q[2]; } p;
  #pragma unroll
  for (int b = 0; b < NB; b++) {
    p.h[b * 2]     = (_Float16)(w10[b] * n0);
    p.h[b * 2 + 1] = (_Float16)(w11[b] * n1);
  }
  *(uint4*)&c1[(size_t)i * 16]     = p.q[0];
  *(uint4*)&c1[(size_t)i * 16 + 8] = p.q[1];
  #pragma unroll
  for (int b = 0; b < NB; b++) {
    p.h[b * 2]     = (_Float16)(w20[b] * n0);
    p.h[b * 2 + 1] = (_Float16)(w21[b] * n1);
  }
  *(uint4*)&c2[(size_t)i * 16]     = p.q[0];
  *(uint4*)&c2[(size_t)i * 16 + 8] = p.q[1];
}

// ---------------------------------------------------------------------------
// Aggregation: one wave per dst node; edge-pair inner loop with fdot2.
// agg[v][kk*8+b] = sum_edges c[slot][b] * hf[psrc[slot]][kk]   (fp16)
// ---------------------------------------------------------------------------
__global__ __launch_bounds__(256) void k_agg(
    const int* __restrict__ rowst, const int* __restrict__ cnt,
    const int* __restrict__ psrc, const _Float16* __restrict__ cpair,
    const _Float16* __restrict__ hf,
    _Float16* __restrict__ agg, int N)
{
  int v = blockIdx.x * 4 + (threadIdx.x >> 6);
  if (v >= N) return;
  int lane = threadIdx.x & 63;
  const uint_t* hf32 = (const uint_t*)hf;
  const int beg = rowst[v];                    // even by construction
  const int npairs = (cnt[v] + 1) >> 1;
  const uint_t* cp = (const uint_t*)cpair + (size_t)(beg >> 1) * 8;
  const int* ps = psrc + beg;

  float ax[NB] = {}, ay[NB] = {};
  int i = 0;
  for (; i + 2 <= npairs; i += 2) {
    int s0 = ps[2*i + 0], s1 = ps[2*i + 1];
    int s2 = ps[2*i + 2], s3 = ps[2*i + 3];
    uint_t u0 = hf32[(size_t)s0 * 64 + lane];
    uint_t u1 = hf32[(size_t)s1 * 64 + lane];
    uint_t u2 = hf32[(size_t)s2 * 64 + lane];
    uint_t u3 = hf32[(size_t)s3 * 64 + lane];
    uint_t lo01 = __builtin_amdgcn_perm(u0, u1, 0x01000504);
    uint_t hi01 = __builtin_amdgcn_perm(u0, u1, 0x03020706);
    uint_t lo23 = __builtin_amdgcn_perm(u2, u3, 0x01000504);
    uint_t hi23 = __builtin_amdgcn_perm(u2, u3, 0x03020706);
    #pragma unroll
    for (int b = 0; b < NB; b++) {
      uint_t ca = cp[(size_t)i * 8 + b];
      uint_t cb = cp[(size_t)(i + 1) * 8 + b];
      ax[b] = fdot2(ca, lo01, ax[b]);
      ay[b] = fdot2(ca, hi01, ay[b]);
      ax[b] = fdot2(cb, lo23, ax[b]);
      ay[b] = fdot2(cb, hi23, ay[b]);
    }
  }
  if (i < npairs) {
    int s0 = ps[2*i + 0], s1 = ps[2*i + 1];
    uint_t u0 = hf32[(size_t)s0 * 64 + lane];
    uint_t u1 = hf32[(size_t)s1 * 64 + lane];
    uint_t lo01 = __builtin_amdgcn_perm(u0, u1, 0x01000504);
    uint_t hi01 = __builtin_amdgcn_perm(u0, u1, 0x03020706);
    #pragma unroll
    for (int b = 0; b < NB; b++) {
      uint_t ca = cp[(size_t)i * 8 + b];
      ax[b] = fdot2(ca, lo01, ax[b]);
      ay[b] = fdot2(ca, hi01, ay[b]);
    }
  }

  union { _Float16 e[8]; uint4 q; } p0, p1;
  #pragma unroll
  for (int b = 0; b < NB; b++) { p0.e[b] = (_Float16)ax[b]; p1.e[b] = (_Float16)ay[b]; }
  uint4* dstp = (uint4*)&agg[(size_t)v * 1024 + lane * 16];
  dstp[0] = p0.q;
  dstp[1] = p1.q;
}

// ---------------------------------------------------------------------------
// MFMA GEMM, K=1152, BK=64, LDS-shared B with global_load_lds double-buffer.
// ---------------------------------------------------------------------------
template <int LAYER>
__global__ __launch_bounds__(256) void k_mm(
    const _Float16* __restrict__ agg,   // [N][1024]
    const _Float16* __restrict__ hf,    // [N][128]
    const _Float16* __restrict__ WcA,   // [36][128][32]
    const float* __restrict__ bias,
    float* __restrict__ outf, _Float16* __restrict__ outh, int N)
{
  __shared__ _Float16 sB[2][4096];      // 2 x 8KB

  const int n0   = blockIdx.x * 64;
  const int wv   = threadIdx.x >> 6;
  const int lane = threadIdx.x & 63;
  const int l15  = lane & 15, l4 = lane >> 4;

  int nodeL = n0 + lane; if (nodeL >= N) nodeL = N - 1;   // stage-source clamp

  f32x4 acc[2][4];
  #pragma unroll
  for (int a = 0; a < 2; a++)
    #pragma unroll
    for (int b = 0; b < 4; b++) acc[a][b] = (f32x4)0.f;

  const int fbase = wv * 32 + l15;      // + mf*16
  const int koff  = l4 * 8;

  auto STAGE = [&](int buf, int t) {
    const _Float16 *g0, *g1;
    if (t < 16) {
      g0 = &agg[(size_t)nodeL * 1024 + (2 * t)     * 32 + wv * 8];
      g1 = &agg[(size_t)nodeL * 1024 + (2 * t + 1) * 32 + wv * 8];
    } else {
      g0 = &hf[(size_t)nodeL * DD + (2 * t - 32) * 32 + wv * 8];
      g1 = &hf[(size_t)nodeL * DD + (2 * t - 31) * 32 + wv * 8];
    }
    gld_lds16(g0, &sB[buf][ wv      * 512]);
    gld_lds16(g1, &sB[buf][(wv + 4) * 512]);
  };

  auto COMPUTE = [&](int buf, int t) {
    #pragma unroll
    for (int sub = 0; sub < 2; sub++) {
      const int ks = 2 * t + sub;
      half8v af[2], bfr[4];
      #pragma unroll
      for (int mf = 0; mf < 2; mf++)
        af[mf] = *(const half8v*)&WcA[((size_t)ks * DD + fbase + mf * 16) * 32 + koff];
      #pragma unroll
      for (int nf = 0; nf < 4; nf++)
        bfr[nf] = *(const half8v*)&sB[buf][(l4 + sub * 4) * 512 + (nf * 16 + l15) * 8];
      #pragma unroll
      for (int mf = 0; mf < 2; mf++)
        #pragma unroll
        for (int nf = 0; nf < 4; nf++)
          acc[mf][nf] = __builtin_amdgcn_mfma_f32_16x16x32_f16(af[mf], bfr[nf], acc[mf][nf], 0, 0, 0);
    }
  };

  STAGE(0, 0);
  __syncthreads();
  int cur = 0;
  for (int t = 0; t < 17; t++) {
    STAGE(cur ^ 1, t + 1);
    COMPUTE(cur, t);
    __syncthreads();
    cur ^= 1;
  }
  COMPUTE(cur, 17);

  #pragma unroll
  for (int mf = 0; mf < 2; mf++)
    #pragma unroll
    for (int nf = 0; nf < 4; nf++) {
      int n = n0 + nf * 16 + l15;
      if (n >= N) continue;
      int feat = wv * 32 + mf * 16 + l4 * 4;
      if (LAYER == 1) {
        union { _Float16 e[4]; uint2 q; } p;
        #pragma unroll
        for (int r = 0; r < 4; r++)
          p.e[r] = (_Float16)fmaxf(acc[mf][nf][r] + bias[feat + r], 0.f);
        *(uint2*)&outh[(size_t)n * DD + feat] = p.q;
      } else {
        float4 o;
        o.x = acc[mf][nf][0] + bias[feat + 0];
        o.y = acc[mf][nf][1] + bias[feat + 1];
        o.z = acc[mf][nf][2] + bias[feat + 2];
        o.w = acc[mf][nf][3] + bias[feat + 3];
        *(float4*)&outf[(size_t)n * DD + feat] = o;
      }
    }
}

extern "C" void kernel_launch(void* const* d_in, const int* in_sizes, int n_in,
                              void* d_out, int out_size, void* d_ws, size_t ws_size,
                              hipStream_t stream)
{
  const int*   h_ids     = (const int*)d_in[0];
  const int*   src       = (const int*)d_in[1];
  const int*   dst       = (const int*)d_in[2];
  const int*   etype     = (const int*)d_in[3];
  const float* norm      = (const float*)d_in[4];
  const float* embedding = (const float*)d_in[5];
  const float* w_comp1   = (const float*)d_in[6];
  const float* bases1    = (const float*)d_in[7];
  const float* loop_w1   = (const float*)d_in[8];
  const float* bias1     = (const float*)d_in[9];
  const float* w_comp2   = (const float*)d_in[10];
  const float* bases2    = (const float*)d_in[11];
  const float* loop_w2   = (const float*)d_in[12];
  const float* bias2     = (const float*)d_in[13];

  const int N = in_sizes[0];
  const int E = in_sizes[1];
  const int S = (E + N) & ~1;           // padded-slot capacity (even)
  const int NPAIR = S >> 1;
  const int NBLK = (N + 255) / 256;     // <= 256 (N <= 65536)

  // ---- workspace carve-up (256B aligned) ----
  char* base = (char*)d_ws;
  size_t off = 0;
  auto alloc = [&](size_t bytes) -> char* {
    char* p = base + off;
    off += (bytes + 255) & ~(size_t)255;
    return p;
  };
  _Float16* agg  = (_Float16*)alloc((size_t)N * 1024 * 2);   // 102.4 MB
  _Float16* hfp  = (_Float16*)alloc((size_t)N * DD * 2);     // 12.8 MB
  _Float16* h1h  = (_Float16*)alloc((size_t)N * DD * 2);     // 12.8 MB
  _Float16* WcA  = (_Float16*)alloc((size_t)2 * 36 * DD * 32 * 2);
  int*      cnt    = (int*)   alloc((size_t)2 * N * 4);      // cnt + cursor
  int*      cursor = cnt + N;
  int*      rowst  = (int*)   alloc((size_t)N * 4);
  int*      bsum   = (int*)   alloc(256 * 4);
  int*      boff   = (int*)   alloc(256 * 4);
  int*      perm   = (int*)   alloc((size_t)S * 4);
  int*      psrc   = (int*)   alloc((size_t)S * 4);
  _Float16* c1     = (_Float16*)alloc((size_t)S * 8 * 2);    // ~10.4 MB
  _Float16* c2     = (_Float16*)alloc((size_t)S * 8 * 2);    // ~10.4 MB
  float*    out    = (float*)d_out;

  // ---- build padded CSR by dst (reused by both layers) ----
  k_zero <<<(2 * N + 255) / 256, 256, 0, stream>>>(cnt, 2 * N);
  k_fill <<<(S + 255) / 256, 256, 0, stream>>>(perm, -1, S);
  k_hist <<<(E + 255) / 256, 256, 0, stream>>>(dst, cnt, E);
  k_bsum <<<NBLK, 256, 0, stream>>>(cnt, bsum, N);
  k_scanb<<<1, 256, 0, stream>>>(bsum, boff, NBLK);
  k_scan3<<<NBLK, 256, 0, stream>>>(cnt, boff, rowst, N);
  k_place<<<(E + 255) / 256, 256, 0, stream>>>(dst, rowst, cursor, perm, E);
  k_payload_pair<<<(NPAIR + 255) / 256, 256, 0, stream>>>(
      perm, src, etype, norm, w_comp1, w_comp2, psrc, c1, c2, NPAIR);

  // ---- weights -> fp16 A-coalesced layout ----
  k_prep_w<<<(2 * 36 * DD * 32 + 255) / 256, 256, 0, stream>>>(bases1, loop_w1, bases2, loop_w2, WcA);

  dim3 gmm((N + 63) / 64);
  int gagg = (N + 3) / 4;

  // ---- layer 1 ----
  k_cast<<<(N * (DD / 8) + 255) / 256, 256, 0, stream>>>(embedding, h_ids, hfp, N);
  k_agg<<<gagg, 256, 0, stream>>>(rowst, cnt, psrc, c1, hfp, agg, N);
  k_mm<1><<<gmm, 256, 0, stream>>>(agg, hfp, WcA, bias1, nullptr, h1h, N);

  // ---- layer 2 ----
  k_agg<<<gagg, 256, 0, stream>>>(rowst, cnt, psrc, c2, h1h, agg, N);
  k_mm<2><<<gmm, 256, 0, stream>>>(agg, h1h, WcA + (size_t)36 * DD * 32, bias2, out, nullptr, N);
}